// Round 4
// baseline (1781.964 us; speedup 1.0000x reference)
//
#include <hip/hip_runtime.h>
#include <math.h>

#define NN 100000
#define PADN 100096    // 782*128
#define NBLK 782
#define HH 512
#define KK 128
#define BETA 100.0f
#define EPSF 1e-8f
#define ITERS 11
#define NSPLIT 128
#define NCHUNK (PADN / 64)  // 1564

typedef __attribute__((ext_vector_type(8))) short short8v;
typedef __attribute__((ext_vector_type(4))) float float4v;

typedef const __attribute__((address_space(1))) void* gas_t;
typedef __attribute__((address_space(3))) void* las_t;

__device__ __forceinline__ void gload16(const void* g, void* l) {
  __builtin_amdgcn_global_load_lds((gas_t)g, (las_t)l, 16, 0, 0);
}

__device__ __forceinline__ unsigned short f2bf(float x) {
  unsigned int u = __float_as_uint(x);
  unsigned int r = (u + 0x7fff + ((u >> 16) & 1)) >> 16;
  return (unsigned short)r;
}
__device__ __forceinline__ float bf2f(unsigned short b) {
  return __uint_as_float((unsigned int)b << 16);
}

__device__ __forceinline__ float wave_reduce_sum(float v) {
#pragma unroll
  for (int off = 32; off > 0; off >>= 1) v += __shfl_xor(v, off);
  return v;
}
__device__ __forceinline__ float softplusf(float x) {
  return fmaxf(x, 0.0f) + log1pf(expf(-fabsf(x)));
}

// ---- prep: inv_norm[i] = 1/(||pos_i||+eps); colsum[h] = sum_i pos[i][h]
__global__ void prep_kernel(const float* __restrict__ pos,
                            float* __restrict__ inv_norm,
                            float* __restrict__ colsum) {
  int w = threadIdx.x >> 6, lane = threadIdx.x & 63;
  int gw = blockIdx.x * 4 + w;
  float cpart[8] = {0, 0, 0, 0, 0, 0, 0, 0};
  for (int row = gw; row < NN; row += 1024) {
    const float* p = pos + (size_t)row * HH;
    float ss = 0.f;
#pragma unroll
    for (int j = 0; j < 8; ++j) {
      float v = p[lane + 64 * j];
      ss += v * v;
      cpart[j] += v;
    }
    ss = wave_reduce_sum(ss);
    if (lane == 0) inv_norm[row] = 1.0f / (sqrtf(ss) + EPSF);
  }
  __shared__ float cs[HH];
  cs[threadIdx.x] = 0.f;
  cs[threadIdx.x + 256] = 0.f;
  __syncthreads();
#pragma unroll
  for (int j = 0; j < 8; ++j) atomicAdd(&cs[lane + 64 * j], cpart[j]);
  __syncthreads();
  atomicAdd(&colsum[threadIdx.x], cs[threadIdx.x]);
  atomicAdd(&colsum[threadIdx.x + 256], cs[threadIdx.x + 256]);
}

// ---- one-time: normalized bf16 copies of pos: row-major (posb) + transposed (posbT)
__launch_bounds__(256)
__global__ void convert_kernel(const float* __restrict__ pos, const float* __restrict__ inv_norm,
                               unsigned short* __restrict__ posb, unsigned short* __restrict__ posbT) {
  __shared__ unsigned short tile[64][72];
  int t = threadIdx.x;
  int i0 = blockIdx.x * 64, h0 = blockIdx.y * 64;
  int r = t >> 2, cg = (t & 3) * 16;
  int gi = i0 + r;
  bool valid = gi < NN;
  float inv = valid ? inv_norm[gi] : 0.f;
  unsigned short v16[16];
#pragma unroll
  for (int q = 0; q < 4; ++q) {
    float4 f;
    if (valid) f = *(const float4*)&pos[(size_t)gi * HH + h0 + cg + q * 4];
    else { f.x = 0.f; f.y = 0.f; f.z = 0.f; f.w = 0.f; }
    v16[q * 4 + 0] = f2bf(f.x * inv);
    v16[q * 4 + 1] = f2bf(f.y * inv);
    v16[q * 4 + 2] = f2bf(f.z * inv);
    v16[q * 4 + 3] = f2bf(f.w * inv);
  }
#pragma unroll
  for (int q = 0; q < 2; ++q) {
    short8v o;
#pragma unroll
    for (int e = 0; e < 8; ++e) o[e] = (short)v16[q * 8 + e];
    *(short8v*)&posb[(size_t)gi * HH + h0 + cg + q * 8] = o;
  }
#pragma unroll
  for (int q = 0; q < 16; ++q) tile[cg + q][r] = v16[q];
  __syncthreads();
  int h = t >> 2, ig = (t & 3) * 16;
#pragma unroll
  for (int q = 0; q < 2; ++q)
    *(short8v*)&posbT[(size_t)(h0 + h) * PADN + i0 + ig + q * 8] =
        *(const short8v*)&tile[h][ig + q * 8];
}

// ---- gs[h] = sigmoid(colsum[h]/N)
__global__ void gs_kernel(const float* __restrict__ colsum, float* __restrict__ gs) {
  int t = threadIdx.x;
  float m = colsum[t] * (1.0f / NN);
  gs[t] = 1.0f / (1.0f + expf(-m));
}

// ---- Ws[j] = sum_h W[j][h]*gs[h]
__global__ void wsum_kernel(const float* __restrict__ W, const float* __restrict__ gs,
                            float* __restrict__ Ws) {
  int w = threadIdx.x >> 6, lane = threadIdx.x & 63;
  int row = blockIdx.x * 4 + w;
  const float* Wr = W + (size_t)row * HH;
  float s = 0.f;
#pragma unroll
  for (int j = 0; j < 8; ++j) s += Wr[lane + 64 * j] * gs[lane + 64 * j];
  s = wave_reduce_sum(s);
  if (lane == 0) Ws[row] = s;
}

// ---- mu_norm (bf16) = mu / ||mu||; zero cluster_r
__global__ void norm_mu_kernel(const float* __restrict__ mu, unsigned short* __restrict__ mub,
                               float* __restrict__ cluster_r) {
  int k = blockIdx.x, t = threadIdx.x;
  float v0 = mu[k * HH + t], v1 = mu[k * HH + t + 256];
  float ss = v0 * v0 + v1 * v1;
  ss = wave_reduce_sum(ss);
  __shared__ float red[4];
  if ((t & 63) == 0) red[t >> 6] = ss;
  __syncthreads();
  float inv = 1.0f / sqrtf(red[0] + red[1] + red[2] + red[3]);
  mub[k * HH + t] = f2bf(v0 * inv);
  mub[k * HH + t + 256] = f2bf(v1 * inv);
  if (t == 0) cluster_r[k] = 0.f;
}

// ---- MFMA dist + fused softmax. A (posb) LDS double-buffered; B (mub, L2-hot) direct from global.
__launch_bounds__(256, 3)
__global__ void dist_mfma(const unsigned short* __restrict__ posb,
                          const unsigned short* __restrict__ mub,
                          unsigned short* __restrict__ rbf,
                          unsigned short* __restrict__ rbfT,
                          float* __restrict__ cluster_r,
                          int write_rbf) {
  __shared__ __align__(16) unsigned short smem[17408];  // 34.8KB union
  unsigned short (*As)[8192] = (unsigned short(*)[8192])smem;  // 2 x 16KB staging
  unsigned short* rT = smem;                                   // [128 c][136] epilogue
  __shared__ float redM[2][128];
  __shared__ float redS[2][128];

  int t = threadIdx.x;
  int w = t >> 6, l = t & 63;
  int wr = w >> 1, wc = w & 1;
  int i0 = blockIdx.x * 128;

  float4v acc[4][4];
#pragma unroll
  for (int mi = 0; mi < 4; ++mi)
#pragma unroll
    for (int ni = 0; ni < 4; ++ni) acc[mi][ni] = (float4v){0.f, 0.f, 0.f, 0.f};

  auto stage = [&](int buf, int ch) {
    int h0 = ch * 64;
#pragma unroll
    for (int j = 0; j < 4; ++j) {
      int v = w * 4 + j;
      int row = v * 8 + (l >> 3);
      int col = (l & 7) * 8;
      gload16(posb + (size_t)(i0 + row) * HH + h0 + col, &As[buf][v * 512]);
    }
  };

  stage(0, 0);
  __syncthreads();
  int cur = 0;
  for (int ch = 0; ch < 8; ++ch) {
    if (ch < 7) stage(cur ^ 1, ch + 1);
#pragma unroll
    for (int ks = 0; ks < 2; ++ks) {
      short8v af[4], bfr[4];
      int k = ks * 32 + (l >> 4) * 8;
#pragma unroll
      for (int ni = 0; ni < 4; ++ni) {
        int row = wc * 64 + ni * 16 + (l & 15);
        bfr[ni] = *(const short8v*)&mub[(size_t)row * HH + ch * 64 + k];
      }
#pragma unroll
      for (int mi = 0; mi < 4; ++mi) {
        int row = wr * 64 + mi * 16 + (l & 15);
        af[mi] = *(const short8v*)&As[cur][row * 64 + k];
      }
#pragma unroll
      for (int mi = 0; mi < 4; ++mi)
#pragma unroll
        for (int ni = 0; ni < 4; ++ni)
          acc[mi][ni] = __builtin_amdgcn_mfma_f32_16x16x32_bf16(af[mi], bfr[ni], acc[mi][ni], 0, 0, 0);
    }
    __syncthreads();
    cur ^= 1;
  }

  // ---- softmax epilogue. row(local) = wr*64+mi*16+(l>>4)*4+j, col = wc*64+ni*16+(l&15)
  float wmax[4][4];
#pragma unroll
  for (int mi = 0; mi < 4; ++mi)
#pragma unroll
    for (int j = 0; j < 4; ++j) {
      float m = fmaxf(fmaxf(acc[mi][0][j], acc[mi][1][j]), fmaxf(acc[mi][2][j], acc[mi][3][j])) * BETA;
      m = fmaxf(m, __shfl_xor(m, 1));
      m = fmaxf(m, __shfl_xor(m, 2));
      m = fmaxf(m, __shfl_xor(m, 4));
      m = fmaxf(m, __shfl_xor(m, 8));
      wmax[mi][j] = m;
    }
  if ((l & 15) == 0) {
#pragma unroll
    for (int mi = 0; mi < 4; ++mi)
#pragma unroll
      for (int j = 0; j < 4; ++j)
        redM[wc][wr * 64 + mi * 16 + (l >> 4) * 4 + j] = wmax[mi][j];
  }
  __syncthreads();
  float fm[4][4];
#pragma unroll
  for (int mi = 0; mi < 4; ++mi)
#pragma unroll
    for (int j = 0; j < 4; ++j) {
      int row = wr * 64 + mi * 16 + (l >> 4) * 4 + j;
      fm[mi][j] = fmaxf(redM[0][row], redM[1][row]);
    }
#pragma unroll
  for (int mi = 0; mi < 4; ++mi)
#pragma unroll
    for (int j = 0; j < 4; ++j) {
      float s = 0.f;
#pragma unroll
      for (int ni = 0; ni < 4; ++ni) {
        float e = __expf(acc[mi][ni][j] * BETA - fm[mi][j]);
        acc[mi][ni][j] = e;
        s += e;
      }
      s += __shfl_xor(s, 1);
      s += __shfl_xor(s, 2);
      s += __shfl_xor(s, 4);
      s += __shfl_xor(s, 8);
      wmax[mi][j] = s;  // reuse
    }
  if ((l & 15) == 0) {
#pragma unroll
    for (int mi = 0; mi < 4; ++mi)
#pragma unroll
      for (int j = 0; j < 4; ++j)
        redS[wc][wr * 64 + mi * 16 + (l >> 4) * 4 + j] = wmax[mi][j];
  }
  __syncthreads();

  float cpart[4] = {0.f, 0.f, 0.f, 0.f};
#pragma unroll
  for (int mi = 0; mi < 4; ++mi)
#pragma unroll
    for (int j = 0; j < 4; ++j) {
      int row = wr * 64 + mi * 16 + (l >> 4) * 4 + j;
      float invs = 1.0f / (redS[0][row] + redS[1][row]);
      bool valid = (i0 + row) < NN;
#pragma unroll
      for (int ni = 0; ni < 4; ++ni) {
        float rv = acc[mi][ni][j] * invs;
        if (valid) cpart[ni] += rv;
        rT[(wc * 64 + ni * 16 + (l & 15)) * 136 + row] = f2bf(rv);
      }
    }
#pragma unroll
  for (int ni = 0; ni < 4; ++ni) {
    float c = cpart[ni];
    c += __shfl_xor(c, 16);
    c += __shfl_xor(c, 32);
    if (l < 16) atomicAdd(&cluster_r[wc * 64 + ni * 16 + l], c);
  }
  __syncthreads();

  {
    int c = t >> 1, half = t & 1;
    const unsigned short* src = &rT[c * 136 + half * 64];
    unsigned short* dst = &rbfT[(size_t)c * PADN + i0 + half * 64];
#pragma unroll
    for (int q = 0; q < 8; ++q)
      *(short8v*)(dst + q * 8) = *(const short8v*)(src + q * 8);
  }
  if (write_rbf) {
    int i = t >> 1, chalf = t & 1;
#pragma unroll
    for (int q = 0; q < 8; ++q) {
      short8v v;
#pragma unroll
      for (int e = 0; e < 8; ++e) v[e] = (short)rT[(chalf * 64 + q * 8 + e) * 136 + i];
      *(short8v*)&rbf[(size_t)(i0 + i) * KK + chalf * 64 + q * 8] = v;
    }
  }
}

// ---- MFMA mu update. B (posbT) LDS double-buffered; A (rbfT, 4x L2 reuse) direct from global.
__launch_bounds__(256, 3)
__global__ void muup_mfma(const unsigned short* __restrict__ rbfT,
                          const unsigned short* __restrict__ posbT,
                          unsigned short* __restrict__ part) {
  __shared__ __align__(16) unsigned short Bs[2][8192];  // posT tile: [h 128][i 64]
  int t = threadIdx.x;
  int w = t >> 6, l = t & 63;
  int wr = w >> 1, wc = w & 1;
  int ht = blockIdx.x, s = blockIdx.y;

  float4v acc[4][4];
#pragma unroll
  for (int mi = 0; mi < 4; ++mi)
#pragma unroll
    for (int ni = 0; ni < 4; ++ni) acc[mi][ni] = (float4v){0.f, 0.f, 0.f, 0.f};

  auto stage = [&](int buf, int ch) {
    size_t ib = (size_t)ch * 64;
#pragma unroll
    for (int j = 0; j < 4; ++j) {
      int v = w * 4 + j;
      int row = v * 8 + (l >> 3);
      int col = (l & 7) * 8;
      gload16(posbT + (size_t)(ht * 128 + row) * PADN + ib + col, &Bs[buf][v * 512]);
    }
  };

  int ch = s;
  stage(0, ch);
  __syncthreads();
  int cur = 0;
  for (; ch < NCHUNK; ch += NSPLIT) {
    int nxt = ch + NSPLIT;
    if (nxt < NCHUNK) stage(cur ^ 1, nxt);
    size_t ib = (size_t)ch * 64;
#pragma unroll
    for (int ks = 0; ks < 2; ++ks) {
      short8v af[4], bfr[4];
      int k = ks * 32 + (l >> 4) * 8;
#pragma unroll
      for (int mi = 0; mi < 4; ++mi) {
        int row = wr * 64 + mi * 16 + (l & 15);
        af[mi] = *(const short8v*)&rbfT[(size_t)row * PADN + ib + k];
      }
#pragma unroll
      for (int ni = 0; ni < 4; ++ni) {
        int row = wc * 64 + ni * 16 + (l & 15);
        bfr[ni] = *(const short8v*)&Bs[cur][row * 64 + k];
      }
#pragma unroll
      for (int mi = 0; mi < 4; ++mi)
#pragma unroll
        for (int ni = 0; ni < 4; ++ni)
          acc[mi][ni] = __builtin_amdgcn_mfma_f32_16x16x32_bf16(af[mi], bfr[ni], acc[mi][ni], 0, 0, 0);
    }
    __syncthreads();
    cur ^= 1;
  }
#pragma unroll
  for (int mi = 0; mi < 4; ++mi)
#pragma unroll
    for (int ni = 0; ni < 4; ++ni)
#pragma unroll
      for (int j = 0; j < 4; ++j) {
        int c = wr * 64 + mi * 16 + (l >> 4) * 4 + j;
        int hh = wc * 64 + ni * 16 + (l & 15);
        part[((size_t)s * KK + c) * HH + ht * 128 + hh] = f2bf(acc[mi][ni][j]);
      }
}

// ---- mu[c][h] = (sum_s part[s][c][h]) / cluster_r[c]; also mubT bf16 [h][k]
__global__ void fin_mu_kernel(const unsigned short* __restrict__ part,
                              const float* __restrict__ cluster_r,
                              float* __restrict__ mu, unsigned short* __restrict__ mubT) {
  int o = blockIdx.x * 256 + threadIdx.x;  // 65536 outputs
  int c = o >> 9, hh = o & 511;
  float inv = 1.0f / cluster_r[c];
  float sum = 0.f;
#pragma unroll 8
  for (int s2 = 0; s2 < NSPLIT; ++s2) sum += bf2f(part[((size_t)s2 * KK + c) * HH + hh]);
  float v = sum * inv;
  mu[o] = v;
  mubT[(size_t)hh * KK + c] = f2bf(v);
}

// ---- MFMA loss: cs = sigmoid(r@mu) via MFMA; sigma -> LDS; vectorized row-dot phase.
// pos dots use normalized posb * norm (norm = 1/inv_norm, exact recovery).
__launch_bounds__(512, 4)
__global__ void loss_mfma(const unsigned short* __restrict__ rbf,
                          const unsigned short* __restrict__ mubT,
                          const unsigned short* __restrict__ posb,
                          const float* __restrict__ neg,
                          const float* __restrict__ inv_norm,
                          const float* __restrict__ Wsv, float* __restrict__ loss_accum) {
  __shared__ __align__(16) unsigned short rS[128 * 128];   // 32KB [i][k] swizzled
  __shared__ __align__(16) unsigned short BsU[128 * 136];  // 34.8KB: MFMA B (swizzled, 32KB) / csS [row][136]
  __shared__ float WsS[HH];
  __shared__ float pcS[128], ncS[128], pgS[128], ngS[128];
  int t = threadIdx.x;
  int w = t >> 6, l = t & 63;
  int wr = w >> 1, wc = w & 1;
  int i0 = blockIdx.x * 128;

  // stage rS once (swizzled source -> linear LDS; read-side applies same XOR)
  {
    const char* gb = (const char*)rbf + (size_t)i0 * KK * 2;
#pragma unroll
    for (int j = 0; j < 4; ++j) {
      int v = w * 4 + j;
      int row = v * 4 + (l >> 4);
      int cb = ((l & 15) * 16) ^ ((row & 7) << 4);
      gload16(gb + (size_t)row * 256 + cb, (char*)rS + v * 1024);
    }
  }
  WsS[t] = Wsv[t];
  if (t < 128) {
    pcS[t] = 0.f; ncS[t] = 0.f; pgS[t] = 0.f; ngS[t] = 0.f;
  }

  for (int p = 0; p < 4; ++p) {
    __syncthreads();  // (a) prev dot done with csS; p=0: rS/init ready after this (vmcnt drained)
    {
      const char* gb = (const char*)mubT + (size_t)p * 128 * 256;
#pragma unroll
      for (int j = 0; j < 4; ++j) {
        int v = w * 4 + j;
        int row = v * 4 + (l >> 4);
        int cb = ((l & 15) * 16) ^ ((row & 7) << 4);
        gload16(gb + (size_t)row * 256 + cb, (char*)BsU + v * 1024);
      }
    }
    __syncthreads();  // (b) BsU ready

    float4v acc[2][4];
#pragma unroll
    for (int mi = 0; mi < 2; ++mi)
#pragma unroll
      for (int ni = 0; ni < 4; ++ni) acc[mi][ni] = (float4v){0.f, 0.f, 0.f, 0.f};

#pragma unroll
    for (int ks = 0; ks < 4; ++ks) {
      short8v af[2], bfr[4];
      int kb = ks * 64 + (l >> 4) * 16;
#pragma unroll
      for (int mi = 0; mi < 2; ++mi) {
        int row = wr * 32 + mi * 16 + (l & 15);
        af[mi] = *(const short8v*)((const char*)rS + row * 256 + (kb ^ ((row & 7) << 4)));
      }
#pragma unroll
      for (int ni = 0; ni < 4; ++ni) {
        int hrow = wc * 64 + ni * 16 + (l & 15);
        bfr[ni] = *(const short8v*)((const char*)BsU + hrow * 256 + (kb ^ ((hrow & 7) << 4)));
      }
#pragma unroll
      for (int mi = 0; mi < 2; ++mi)
#pragma unroll
        for (int ni = 0; ni < 4; ++ni)
          acc[mi][ni] = __builtin_amdgcn_mfma_f32_16x16x32_bf16(af[mi], bfr[ni], acc[mi][ni], 0, 0, 0);
    }
    __syncthreads();  // (c) all MFMA reads of BsU done

    // sigma -> csS (aliases BsU), stride 136 shorts (272B, 16B-aligned rows)
    unsigned short* csS = BsU;
#pragma unroll
    for (int mi = 0; mi < 2; ++mi)
#pragma unroll
      for (int ni = 0; ni < 4; ++ni)
#pragma unroll
        for (int j = 0; j < 4; ++j) {
          int row = wr * 32 + mi * 16 + (l >> 4) * 4 + j;
          int col = wc * 64 + ni * 16 + (l & 15);
          csS[row * 136 + col] = f2bf(1.0f / (1.0f + __expf(-acc[mi][ni][j])));
        }
    __syncthreads();  // (d) csS ready

    // dot phase: 4 threads per row, contiguous 64B per quad per chunk
    {
      int rl = t >> 2;  // 0..127
      int q = t & 3;
      int gi = i0 + rl;
      bool valid = gi < NN;
      float pc = 0.f, nc = 0.f, pg = 0.f, ng = 0.f;
      const unsigned short* pr = posb + (size_t)gi * HH + p * 128;
      const float* nr = neg + (size_t)gi * HH + p * 128;
      const unsigned short* cr = csS + rl * 136;
#pragma unroll
      for (int e = 0; e < 4; ++e) {
        int cb = e * 32 + q * 8;
        short8v cs8 = *(const short8v*)(cr + cb);
        if (valid) {
          short8v pv8 = *(const short8v*)(pr + cb);
          float4 nv0 = *(const float4*)(nr + cb);
          float4 nv1 = *(const float4*)(nr + cb + 4);
#pragma unroll
          for (int u = 0; u < 8; ++u) {
            float sg = bf2f((unsigned short)cs8[u]);
            float pv = bf2f((unsigned short)pv8[u]);
            float nv = (u < 4) ? (&nv0.x)[u] : (&nv1.x)[u - 4];
            float wv = WsS[p * 128 + cb + u];
            pc = fmaf(sg, pv, pc);
            nc = fmaf(sg, nv, nc);
            pg = fmaf(wv, pv, pg);
            ng = fmaf(wv, nv, ng);
          }
        }
      }
      pc += __shfl_xor(pc, 1); pc += __shfl_xor(pc, 2);
      nc += __shfl_xor(nc, 1); nc += __shfl_xor(nc, 2);
      pg += __shfl_xor(pg, 1); pg += __shfl_xor(pg, 2);
      ng += __shfl_xor(ng, 1); ng += __shfl_xor(ng, 2);
      if (q == 0) {
        pcS[rl] += pc;
        ncS[rl] += nc;
        pgS[rl] += pg;
        ngS[rl] += ng;
      }
    }
  }
  __syncthreads();
  if (t < 128) {
    int gi = i0 + t;
    float contrib = 0.f;
    if (gi < NN) {
      float nrm = 1.0f / inv_norm[gi];  // ||pos||+eps: exact un-normalization
      float pg = pgS[t] * nrm;
      float pc = pcS[t] * nrm;
      float ng = ngS[t];
      float nc = ncS[t];
      contrib = 0.5f * (softplusf(-pg) + softplusf(ng)) +
                0.5f * (softplusf(-pc) + softplusf(nc));
    }
    contrib = wave_reduce_sum(contrib);
    if (l == 0) atomicAdd(loss_accum, contrib);
  }
}

__global__ void out_kernel(const float* __restrict__ loss_accum, float* __restrict__ out) {
  out[0] = loss_accum[0] * (1.0f / NN);
}

extern "C" void kernel_launch(void* const* d_in, const int* in_sizes, int n_in,
                              void* d_out, int out_size, void* d_ws, size_t ws_size,
                              hipStream_t stream) {
  const float* pos = (const float*)d_in[0];
  const float* neg = (const float*)d_in[1];
  const float* init = (const float*)d_in[2];
  const float* W = (const float*)d_in[3];
  float* out = (float*)d_out;

  char* ws = (char*)d_ws;
  size_t off = 0;
  auto alloc = [&](size_t bytes) {
    void* p = ws + off;
    off = (off + bytes + 255) & ~(size_t)255;
    return p;
  };
  unsigned short* posb = (unsigned short*)alloc((size_t)PADN * HH * 2);   // 102.5 MB
  unsigned short* posbT = (unsigned short*)alloc((size_t)HH * PADN * 2);  // 102.5 MB
  unsigned short* rbf = (unsigned short*)alloc((size_t)PADN * KK * 2);    // 25.6 MB
  unsigned short* rbfT = (unsigned short*)alloc((size_t)KK * PADN * 2);   // 25.6 MB
  unsigned short* part = (unsigned short*)alloc((size_t)NSPLIT * KK * HH * 2);  // 16.8 MB
  float* inv_norm = (float*)alloc((size_t)NN * 4);
  float* mu = (float*)alloc((size_t)KK * HH * 4);
  unsigned short* mub = (unsigned short*)alloc((size_t)KK * HH * 2);
  unsigned short* mubT = (unsigned short*)alloc((size_t)KK * HH * 2);
  float* cluster_r = (float*)alloc(KK * 4);
  float* colsum = (float*)alloc(HH * 4);
  float* gs = (float*)alloc(HH * 4);
  float* Ws = (float*)alloc(HH * 4);
  float* loss_accum = (float*)alloc(16);

  hipMemsetAsync(colsum, 0, HH * sizeof(float), stream);
  hipMemsetAsync(loss_accum, 0, sizeof(float), stream);
  hipMemcpyAsync(mu, init, (size_t)KK * HH * sizeof(float), hipMemcpyDeviceToDevice, stream);

  prep_kernel<<<256, 256, 0, stream>>>(pos, inv_norm, colsum);
  convert_kernel<<<dim3(PADN / 64, HH / 64), 256, 0, stream>>>(pos, inv_norm, posb, posbT);
  gs_kernel<<<1, 512, 0, stream>>>(colsum, gs);
  wsum_kernel<<<128, 256, 0, stream>>>(W, gs, Ws);

  for (int it = 0; it < ITERS; ++it) {
    norm_mu_kernel<<<KK, 256, 0, stream>>>(mu, mub, cluster_r);
    dist_mfma<<<NBLK, 256, 0, stream>>>(posb, mub, rbf, rbfT, cluster_r, it == ITERS - 1 ? 1 : 0);
    muup_mfma<<<dim3(4, NSPLIT), 256, 0, stream>>>(rbfT, posbT, part);
    fin_mu_kernel<<<KK * HH / 256, 256, 0, stream>>>(part, cluster_r, mu, mubT);
  }

  loss_mfma<<<NBLK, 512, 0, stream>>>(rbf, mubT, posb, neg, inv_norm, Ws, loss_accum);
  out_kernel<<<1, 1, 0, stream>>>(loss_accum, out);
}

// Round 5
// 1464.535 us; speedup vs baseline: 1.2167x; 1.2167x over previous
//
#include <hip/hip_runtime.h>
#include <math.h>

#define NN 100000
#define PADN 100096    // 782*128
#define NBLK 782
#define HH 512
#define KK 128
#define BETA 100.0f
#define EPSF 1e-8f
#define ITERS 11
#define NSPLIT 128
#define NCHUNK (PADN / 64)  // 1564

typedef __attribute__((ext_vector_type(8))) short short8v;
typedef __attribute__((ext_vector_type(4))) float float4v;

typedef const __attribute__((address_space(1))) void* gas_t;
typedef __attribute__((address_space(3))) void* las_t;

__device__ __forceinline__ void gload16(const void* g, void* l) {
  __builtin_amdgcn_global_load_lds((gas_t)g, (las_t)l, 16, 0, 0);
}

__device__ __forceinline__ unsigned short f2bf(float x) {
  unsigned int u = __float_as_uint(x);
  unsigned int r = (u + 0x7fff + ((u >> 16) & 1)) >> 16;
  return (unsigned short)r;
}
__device__ __forceinline__ float bf2f(unsigned short b) {
  return __uint_as_float((unsigned int)b << 16);
}

__device__ __forceinline__ float wave_reduce_sum(float v) {
#pragma unroll
  for (int off = 32; off > 0; off >>= 1) v += __shfl_xor(v, off);
  return v;
}
__device__ __forceinline__ float softplusf(float x) {
  return fmaxf(x, 0.0f) + log1pf(expf(-fabsf(x)));
}

// ---- prep: inv_norm[i] = 1/(||pos_i||+eps); colsum[h] = sum_i pos[i][h]
__global__ void prep_kernel(const float* __restrict__ pos,
                            float* __restrict__ inv_norm,
                            float* __restrict__ colsum) {
  int w = threadIdx.x >> 6, lane = threadIdx.x & 63;
  int gw = blockIdx.x * 4 + w;
  float cpart[8] = {0, 0, 0, 0, 0, 0, 0, 0};
  for (int row = gw; row < NN; row += 1024) {
    const float* p = pos + (size_t)row * HH;
    float ss = 0.f;
#pragma unroll
    for (int j = 0; j < 8; ++j) {
      float v = p[lane + 64 * j];
      ss += v * v;
      cpart[j] += v;
    }
    ss = wave_reduce_sum(ss);
    if (lane == 0) inv_norm[row] = 1.0f / (sqrtf(ss) + EPSF);
  }
  __shared__ float cs[HH];
  cs[threadIdx.x] = 0.f;
  cs[threadIdx.x + 256] = 0.f;
  __syncthreads();
#pragma unroll
  for (int j = 0; j < 8; ++j) atomicAdd(&cs[lane + 64 * j], cpart[j]);
  __syncthreads();
  atomicAdd(&colsum[threadIdx.x], cs[threadIdx.x]);
  atomicAdd(&colsum[threadIdx.x + 256], cs[threadIdx.x + 256]);
}

// ---- one-time: normalized bf16 copies of pos: row-major (posb) + transposed (posbT)
__launch_bounds__(256)
__global__ void convert_kernel(const float* __restrict__ pos, const float* __restrict__ inv_norm,
                               unsigned short* __restrict__ posb, unsigned short* __restrict__ posbT) {
  __shared__ unsigned short tile[64][72];
  int t = threadIdx.x;
  int i0 = blockIdx.x * 64, h0 = blockIdx.y * 64;
  int r = t >> 2, cg = (t & 3) * 16;
  int gi = i0 + r;
  bool valid = gi < NN;
  float inv = valid ? inv_norm[gi] : 0.f;
  unsigned short v16[16];
#pragma unroll
  for (int q = 0; q < 4; ++q) {
    float4 f;
    if (valid) f = *(const float4*)&pos[(size_t)gi * HH + h0 + cg + q * 4];
    else { f.x = 0.f; f.y = 0.f; f.z = 0.f; f.w = 0.f; }
    v16[q * 4 + 0] = f2bf(f.x * inv);
    v16[q * 4 + 1] = f2bf(f.y * inv);
    v16[q * 4 + 2] = f2bf(f.z * inv);
    v16[q * 4 + 3] = f2bf(f.w * inv);
  }
#pragma unroll
  for (int q = 0; q < 2; ++q) {
    short8v o;
#pragma unroll
    for (int e = 0; e < 8; ++e) o[e] = (short)v16[q * 8 + e];
    *(short8v*)&posb[(size_t)gi * HH + h0 + cg + q * 8] = o;
  }
#pragma unroll
  for (int q = 0; q < 16; ++q) tile[cg + q][r] = v16[q];
  __syncthreads();
  int h = t >> 2, ig = (t & 3) * 16;
#pragma unroll
  for (int q = 0; q < 2; ++q)
    *(short8v*)&posbT[(size_t)(h0 + h) * PADN + i0 + ig + q * 8] =
        *(const short8v*)&tile[h][ig + q * 8];
}

// ---- gs[h] = sigmoid(colsum[h]/N)
__global__ void gs_kernel(const float* __restrict__ colsum, float* __restrict__ gs) {
  int t = threadIdx.x;
  float m = colsum[t] * (1.0f / NN);
  gs[t] = 1.0f / (1.0f + expf(-m));
}

// ---- Ws[j] = sum_h W[j][h]*gs[h]
__global__ void wsum_kernel(const float* __restrict__ W, const float* __restrict__ gs,
                            float* __restrict__ Ws) {
  int w = threadIdx.x >> 6, lane = threadIdx.x & 63;
  int row = blockIdx.x * 4 + w;
  const float* Wr = W + (size_t)row * HH;
  float s = 0.f;
#pragma unroll
  for (int j = 0; j < 8; ++j) s += Wr[lane + 64 * j] * gs[lane + 64 * j];
  s = wave_reduce_sum(s);
  if (lane == 0) Ws[row] = s;
}

// ---- mub (bf16) = row / ||row|| from fp32 src; zero cluster_r. Used once on init.
__global__ void norm_mu_kernel(const float* __restrict__ src, unsigned short* __restrict__ mub,
                               float* __restrict__ cluster_r) {
  int k = blockIdx.x, t = threadIdx.x;
  float v0 = src[k * HH + t], v1 = src[k * HH + t + 256];
  float ss = v0 * v0 + v1 * v1;
  ss = wave_reduce_sum(ss);
  __shared__ float red[4];
  if ((t & 63) == 0) red[t >> 6] = ss;
  __syncthreads();
  float inv = 1.0f / sqrtf(red[0] + red[1] + red[2] + red[3]);
  mub[k * HH + t] = f2bf(v0 * inv);
  mub[k * HH + t + 256] = f2bf(v1 * inv);
  if (t == 0) cluster_r[k] = 0.f;
}

// ---- MFMA dist + fused softmax. A,B LDS double-buffered, XOR-swizzled (src-side + read-side).
__launch_bounds__(256, 2)
__global__ void dist_mfma(const unsigned short* __restrict__ posb,
                          const unsigned short* __restrict__ mub,
                          unsigned short* __restrict__ rbf,
                          unsigned short* __restrict__ rbfT,
                          float* __restrict__ cluster_r,
                          int write_rbf) {
  __shared__ __align__(16) unsigned short smem[32768];  // 64KB: As[2][8192] | Bs[2][8192]
  unsigned short* As0 = smem;
  unsigned short* Bs0 = smem + 16384;
  unsigned short* rT = smem;  // [128 c][136] epilogue alias
  __shared__ float redM[2][128];
  __shared__ float redS[2][128];

  int t = threadIdx.x;
  int w = t >> 6, l = t & 63;
  int wr = w >> 1, wc = w & 1;
  int i0 = blockIdx.x * 128;

  float4v acc[4][4];
#pragma unroll
  for (int mi = 0; mi < 4; ++mi)
#pragma unroll
    for (int ni = 0; ni < 4; ++ni) acc[mi][ni] = (float4v){0.f, 0.f, 0.f, 0.f};

  // swizzled source col (shorts): LDS slot (row, (l&7)*16B) gets global col ((l&7)^(l>>3))*16B
  int rsub = l >> 3;
  int scol = ((l & 7) ^ rsub) * 8;  // shorts

  auto stage = [&](int buf, int ch) {
    int h0 = ch * 64;
#pragma unroll
    for (int j = 0; j < 4; ++j) {
      int v = w * 4 + j;
      int row = v * 8 + rsub;
      gload16(posb + (size_t)(i0 + row) * HH + h0 + scol, As0 + buf * 8192 + v * 512);
      gload16(mub + (size_t)row * HH + h0 + scol, Bs0 + buf * 8192 + v * 512);
    }
  };

  stage(0, 0);
  __syncthreads();
  int cur = 0;
  for (int ch = 0; ch < 8; ++ch) {
    if (ch < 7) stage(cur ^ 1, ch + 1);
    const char* ab = (const char*)(As0 + cur * 8192);
    const char* bb = (const char*)(Bs0 + cur * 8192);
#pragma unroll
    for (int ks = 0; ks < 2; ++ks) {
      short8v af[4], bfr[4];
      int kb = ks * 64 + (l >> 4) * 16;  // byte offset in row (0..127)
      int rx = ((l & 7) << 4);           // row&7 == l&7 for fragment rows
#pragma unroll
      for (int mi = 0; mi < 4; ++mi) {
        int row = wr * 64 + mi * 16 + (l & 15);
        af[mi] = *(const short8v*)(ab + row * 128 + (kb ^ rx));
      }
#pragma unroll
      for (int ni = 0; ni < 4; ++ni) {
        int row = wc * 64 + ni * 16 + (l & 15);
        bfr[ni] = *(const short8v*)(bb + row * 128 + (kb ^ rx));
      }
#pragma unroll
      for (int mi = 0; mi < 4; ++mi)
#pragma unroll
        for (int ni = 0; ni < 4; ++ni)
          acc[mi][ni] = __builtin_amdgcn_mfma_f32_16x16x32_bf16(af[mi], bfr[ni], acc[mi][ni], 0, 0, 0);
    }
    __syncthreads();
    cur ^= 1;
  }

  // ---- softmax epilogue. row(local) = wr*64+mi*16+(l>>4)*4+j, col = wc*64+ni*16+(l&15)
  float wmax[4][4];
#pragma unroll
  for (int mi = 0; mi < 4; ++mi)
#pragma unroll
    for (int j = 0; j < 4; ++j) {
      float m = fmaxf(fmaxf(acc[mi][0][j], acc[mi][1][j]), fmaxf(acc[mi][2][j], acc[mi][3][j])) * BETA;
      m = fmaxf(m, __shfl_xor(m, 1));
      m = fmaxf(m, __shfl_xor(m, 2));
      m = fmaxf(m, __shfl_xor(m, 4));
      m = fmaxf(m, __shfl_xor(m, 8));
      wmax[mi][j] = m;
    }
  if ((l & 15) == 0) {
#pragma unroll
    for (int mi = 0; mi < 4; ++mi)
#pragma unroll
      for (int j = 0; j < 4; ++j)
        redM[wc][wr * 64 + mi * 16 + (l >> 4) * 4 + j] = wmax[mi][j];
  }
  __syncthreads();
  float fm[4][4];
#pragma unroll
  for (int mi = 0; mi < 4; ++mi)
#pragma unroll
    for (int j = 0; j < 4; ++j) {
      int row = wr * 64 + mi * 16 + (l >> 4) * 4 + j;
      fm[mi][j] = fmaxf(redM[0][row], redM[1][row]);
    }
#pragma unroll
  for (int mi = 0; mi < 4; ++mi)
#pragma unroll
    for (int j = 0; j < 4; ++j) {
      float s = 0.f;
#pragma unroll
      for (int ni = 0; ni < 4; ++ni) {
        float e = __expf(acc[mi][ni][j] * BETA - fm[mi][j]);
        acc[mi][ni][j] = e;
        s += e;
      }
      s += __shfl_xor(s, 1);
      s += __shfl_xor(s, 2);
      s += __shfl_xor(s, 4);
      s += __shfl_xor(s, 8);
      wmax[mi][j] = s;  // reuse
    }
  if ((l & 15) == 0) {
#pragma unroll
    for (int mi = 0; mi < 4; ++mi)
#pragma unroll
      for (int j = 0; j < 4; ++j)
        redS[wc][wr * 64 + mi * 16 + (l >> 4) * 4 + j] = wmax[mi][j];
  }
  __syncthreads();

  float cpart[4] = {0.f, 0.f, 0.f, 0.f};
#pragma unroll
  for (int mi = 0; mi < 4; ++mi)
#pragma unroll
    for (int j = 0; j < 4; ++j) {
      int row = wr * 64 + mi * 16 + (l >> 4) * 4 + j;
      float invs = 1.0f / (redS[0][row] + redS[1][row]);
      bool valid = (i0 + row) < NN;
#pragma unroll
      for (int ni = 0; ni < 4; ++ni) {
        float rv = acc[mi][ni][j] * invs;
        if (valid) cpart[ni] += rv;
        rT[(wc * 64 + ni * 16 + (l & 15)) * 136 + row] = f2bf(rv);
      }
    }
#pragma unroll
  for (int ni = 0; ni < 4; ++ni) {
    float c = cpart[ni];
    c += __shfl_xor(c, 16);
    c += __shfl_xor(c, 32);
    if (l < 16) atomicAdd(&cluster_r[wc * 64 + ni * 16 + l], c);
  }
  __syncthreads();

  {
    int c = t >> 1, half = t & 1;
    const unsigned short* src = &rT[c * 136 + half * 64];
    unsigned short* dst = &rbfT[(size_t)c * PADN + i0 + half * 64];
#pragma unroll
    for (int q = 0; q < 8; ++q)
      *(short8v*)(dst + q * 8) = *(const short8v*)(src + q * 8);
  }
  if (write_rbf) {
    int i = t >> 1, chalf = t & 1;
#pragma unroll
    for (int q = 0; q < 8; ++q) {
      short8v v;
#pragma unroll
      for (int e = 0; e < 8; ++e) v[e] = (short)rT[(chalf * 64 + q * 8 + e) * 136 + i];
      *(short8v*)&rbf[(size_t)(i0 + i) * KK + chalf * 64 + q * 8] = v;
    }
  }
}

// ---- MFMA mu update. A (rbfT) + B (posbT) LDS double-buffered, XOR-swizzled.
__launch_bounds__(256, 2)
__global__ void muup_mfma(const unsigned short* __restrict__ rbfT,
                          const unsigned short* __restrict__ posbT,
                          unsigned short* __restrict__ part) {
  __shared__ __align__(16) unsigned short smem[32768];  // As[2][8192] | Bs[2][8192]
  unsigned short* As0 = smem;
  unsigned short* Bs0 = smem + 16384;
  int t = threadIdx.x;
  int w = t >> 6, l = t & 63;
  int wr = w >> 1, wc = w & 1;
  int ht = blockIdx.x, s = blockIdx.y;

  float4v acc[4][4];
#pragma unroll
  for (int mi = 0; mi < 4; ++mi)
#pragma unroll
    for (int ni = 0; ni < 4; ++ni) acc[mi][ni] = (float4v){0.f, 0.f, 0.f, 0.f};

  int rsub = l >> 3;
  int scol = ((l & 7) ^ rsub) * 8;  // shorts

  auto stage = [&](int buf, int ch) {
    size_t ib = (size_t)ch * 64;
#pragma unroll
    for (int j = 0; j < 4; ++j) {
      int v = w * 4 + j;
      int row = v * 8 + rsub;
      gload16(rbfT + (size_t)row * PADN + ib + scol, As0 + buf * 8192 + v * 512);
      gload16(posbT + (size_t)(ht * 128 + row) * PADN + ib + scol, Bs0 + buf * 8192 + v * 512);
    }
  };

  int ch = s;
  stage(0, ch);
  __syncthreads();
  int cur = 0;
  for (; ch < NCHUNK; ch += NSPLIT) {
    int nxt = ch + NSPLIT;
    if (nxt < NCHUNK) stage(cur ^ 1, nxt);
    const char* ab = (const char*)(As0 + cur * 8192);
    const char* bb = (const char*)(Bs0 + cur * 8192);
#pragma unroll
    for (int ks = 0; ks < 2; ++ks) {
      short8v af[4], bfr[4];
      int kb = ks * 64 + (l >> 4) * 16;
      int rx = ((l & 7) << 4);
#pragma unroll
      for (int mi = 0; mi < 4; ++mi) {
        int row = wr * 64 + mi * 16 + (l & 15);
        af[mi] = *(const short8v*)(ab + row * 128 + (kb ^ rx));
      }
#pragma unroll
      for (int ni = 0; ni < 4; ++ni) {
        int row = wc * 64 + ni * 16 + (l & 15);
        bfr[ni] = *(const short8v*)(bb + row * 128 + (kb ^ rx));
      }
#pragma unroll
      for (int mi = 0; mi < 4; ++mi)
#pragma unroll
        for (int ni = 0; ni < 4; ++ni)
          acc[mi][ni] = __builtin_amdgcn_mfma_f32_16x16x32_bf16(af[mi], bfr[ni], acc[mi][ni], 0, 0, 0);
    }
    __syncthreads();
    cur ^= 1;
  }
#pragma unroll
  for (int mi = 0; mi < 4; ++mi)
#pragma unroll
    for (int ni = 0; ni < 4; ++ni)
#pragma unroll
      for (int j = 0; j < 4; ++j) {
        int c = wr * 64 + mi * 16 + (l >> 4) * 4 + j;
        int hh = wc * 64 + ni * 16 + (l & 15);
        part[((size_t)s * KK + c) * HH + ht * 128 + hh] = f2bf(acc[mi][ni][j]);
      }
}

// ---- fused fin+norm: v = (sum_s part)/cluster_r; mub = normalize(v); mubT (last iter) = v; cr=0
__global__ void finorm_kernel(const unsigned short* __restrict__ part,
                              float* __restrict__ cluster_r,
                              unsigned short* __restrict__ mub,
                              unsigned short* __restrict__ mubT, int write_mubT) {
  int c = blockIdx.x, t = threadIdx.x;
  float inv = 1.0f / cluster_r[c];
  float s0 = 0.f, s1 = 0.f;
  const unsigned short* pb = part + (size_t)c * HH;
#pragma unroll 4
  for (int s2 = 0; s2 < NSPLIT; ++s2) {
    s0 += bf2f(pb[(size_t)s2 * KK * HH + t]);
    s1 += bf2f(pb[(size_t)s2 * KK * HH + t + 256]);
  }
  float v0 = s0 * inv, v1 = s1 * inv;
  if (write_mubT) {
    mubT[(size_t)t * KK + c] = f2bf(v0);
    mubT[(size_t)(t + 256) * KK + c] = f2bf(v1);
  }
  float ss = v0 * v0 + v1 * v1;
  ss = wave_reduce_sum(ss);
  __shared__ float red[4];
  if ((t & 63) == 0) red[t >> 6] = ss;
  __syncthreads();
  float rn = 1.0f / sqrtf(red[0] + red[1] + red[2] + red[3]);
  mub[c * HH + t] = f2bf(v0 * rn);
  mub[c * HH + t + 256] = f2bf(v1 * rn);
  if (t == 0) cluster_r[c] = 0.f;
}

// ---- MFMA loss: cs = sigmoid(r@mu) via MFMA; sigma -> LDS; vectorized row-dot phase.
// pos dots use normalized posb * norm (norm = 1/inv_norm, exact recovery).
__launch_bounds__(512, 4)
__global__ void loss_mfma(const unsigned short* __restrict__ rbf,
                          const unsigned short* __restrict__ mubT,
                          const unsigned short* __restrict__ posb,
                          const float* __restrict__ neg,
                          const float* __restrict__ inv_norm,
                          const float* __restrict__ Wsv, float* __restrict__ loss_accum) {
  __shared__ __align__(16) unsigned short rS[128 * 128];   // 32KB [i][k] swizzled
  __shared__ __align__(16) unsigned short BsU[128 * 136];  // MFMA B (swizzled) / csS [row][136]
  __shared__ float WsS[HH];
  __shared__ float pcS[128], ncS[128], pgS[128], ngS[128];
  int t = threadIdx.x;
  int w = t >> 6, l = t & 63;
  int wr = w >> 1, wc = w & 1;
  int i0 = blockIdx.x * 128;

  {
    const char* gb = (const char*)rbf + (size_t)i0 * KK * 2;
#pragma unroll
    for (int j = 0; j < 4; ++j) {
      int v = w * 4 + j;
      int row = v * 4 + (l >> 4);
      int cb = ((l & 15) * 16) ^ ((row & 7) << 4);
      gload16(gb + (size_t)row * 256 + cb, (char*)rS + v * 1024);
    }
  }
  WsS[t] = Wsv[t];
  if (t < 128) {
    pcS[t] = 0.f; ncS[t] = 0.f; pgS[t] = 0.f; ngS[t] = 0.f;
  }

  for (int p = 0; p < 4; ++p) {
    __syncthreads();  // (a) prev dot done with csS; p=0: init; barrier drains vmcnt
    {
      const char* gb = (const char*)mubT + (size_t)p * 128 * 256;
#pragma unroll
      for (int j = 0; j < 4; ++j) {
        int v = w * 4 + j;
        int row = v * 4 + (l >> 4);
        int cb = ((l & 15) * 16) ^ ((row & 7) << 4);
        gload16(gb + (size_t)row * 256 + cb, (char*)BsU + v * 1024);
      }
    }
    __syncthreads();  // (b) BsU ready

    float4v acc[2][4];
#pragma unroll
    for (int mi = 0; mi < 2; ++mi)
#pragma unroll
      for (int ni = 0; ni < 4; ++ni) acc[mi][ni] = (float4v){0.f, 0.f, 0.f, 0.f};

#pragma unroll
    for (int ks = 0; ks < 4; ++ks) {
      short8v af[2], bfr[4];
      int kb = ks * 64 + (l >> 4) * 16;
#pragma unroll
      for (int mi = 0; mi < 2; ++mi) {
        int row = wr * 32 + mi * 16 + (l & 15);
        af[mi] = *(const short8v*)((const char*)rS + row * 256 + (kb ^ ((row & 7) << 4)));
      }
#pragma unroll
      for (int ni = 0; ni < 4; ++ni) {
        int hrow = wc * 64 + ni * 16 + (l & 15);
        bfr[ni] = *(const short8v*)((const char*)BsU + hrow * 256 + (kb ^ ((hrow & 7) << 4)));
      }
#pragma unroll
      for (int mi = 0; mi < 2; ++mi)
#pragma unroll
        for (int ni = 0; ni < 4; ++ni)
          acc[mi][ni] = __builtin_amdgcn_mfma_f32_16x16x32_bf16(af[mi], bfr[ni], acc[mi][ni], 0, 0, 0);
    }
    __syncthreads();  // (c) all MFMA reads of BsU done

    unsigned short* csS = BsU;
#pragma unroll
    for (int mi = 0; mi < 2; ++mi)
#pragma unroll
      for (int ni = 0; ni < 4; ++ni)
#pragma unroll
        for (int j = 0; j < 4; ++j) {
          int row = wr * 32 + mi * 16 + (l >> 4) * 4 + j;
          int col = wc * 64 + ni * 16 + (l & 15);
          csS[row * 136 + col] = f2bf(1.0f / (1.0f + __expf(-acc[mi][ni][j])));
        }
    __syncthreads();  // (d) csS ready

    {
      int rl = t >> 2;  // 0..127
      int q = t & 3;
      int gi = i0 + rl;
      bool valid = gi < NN;
      float pc = 0.f, nc = 0.f, pg = 0.f, ng = 0.f;
      const unsigned short* pr = posb + (size_t)gi * HH + p * 128;
      const float* nr = neg + (size_t)gi * HH + p * 128;
      const unsigned short* cr = csS + rl * 136;
#pragma unroll
      for (int e = 0; e < 4; ++e) {
        int cb = e * 32 + q * 8;
        short8v cs8 = *(const short8v*)(cr + cb);
        if (valid) {
          short8v pv8 = *(const short8v*)(pr + cb);
          float4 nv0 = *(const float4*)(nr + cb);
          float4 nv1 = *(const float4*)(nr + cb + 4);
#pragma unroll
          for (int u = 0; u < 8; ++u) {
            float sg = bf2f((unsigned short)cs8[u]);
            float pv = bf2f((unsigned short)pv8[u]);
            float nv = (u < 4) ? (&nv0.x)[u] : (&nv1.x)[u - 4];
            float wv = WsS[p * 128 + cb + u];
            pc = fmaf(sg, pv, pc);
            nc = fmaf(sg, nv, nc);
            pg = fmaf(wv, pv, pg);
            ng = fmaf(wv, nv, ng);
          }
        }
      }
      pc += __shfl_xor(pc, 1); pc += __shfl_xor(pc, 2);
      nc += __shfl_xor(nc, 1); nc += __shfl_xor(nc, 2);
      pg += __shfl_xor(pg, 1); pg += __shfl_xor(pg, 2);
      ng += __shfl_xor(ng, 1); ng += __shfl_xor(ng, 2);
      if (q == 0) {
        pcS[rl] += pc;
        ncS[rl] += nc;
        pgS[rl] += pg;
        ngS[rl] += ng;
      }
    }
  }
  __syncthreads();
  if (t < 128) {
    int gi = i0 + t;
    float contrib = 0.f;
    if (gi < NN) {
      float nrm = 1.0f / inv_norm[gi];  // ||pos||+eps: exact un-normalization
      float pg = pgS[t] * nrm;
      float pc = pcS[t] * nrm;
      float ng = ngS[t];
      float nc = ncS[t];
      contrib = 0.5f * (softplusf(-pg) + softplusf(ng)) +
                0.5f * (softplusf(-pc) + softplusf(nc));
    }
    contrib = wave_reduce_sum(contrib);
    if (l == 0) atomicAdd(loss_accum, contrib);
  }
}

__global__ void out_kernel(const float* __restrict__ loss_accum, float* __restrict__ out) {
  out[0] = loss_accum[0] * (1.0f / NN);
}

extern "C" void kernel_launch(void* const* d_in, const int* in_sizes, int n_in,
                              void* d_out, int out_size, void* d_ws, size_t ws_size,
                              hipStream_t stream) {
  const float* pos = (const float*)d_in[0];
  const float* neg = (const float*)d_in[1];
  const float* init = (const float*)d_in[2];
  const float* W = (const float*)d_in[3];
  float* out = (float*)d_out;

  char* ws = (char*)d_ws;
  size_t off = 0;
  auto alloc = [&](size_t bytes) {
    void* p = ws + off;
    off = (off + bytes + 255) & ~(size_t)255;
    return p;
  };
  unsigned short* posb = (unsigned short*)alloc((size_t)PADN * HH * 2);   // 102.5 MB
  unsigned short* posbT = (unsigned short*)alloc((size_t)HH * PADN * 2);  // 102.5 MB
  unsigned short* rbf = (unsigned short*)alloc((size_t)PADN * KK * 2);    // 25.6 MB
  unsigned short* rbfT = (unsigned short*)alloc((size_t)KK * PADN * 2);   // 25.6 MB
  unsigned short* part = (unsigned short*)alloc((size_t)NSPLIT * KK * HH * 2);  // 16.8 MB
  float* inv_norm = (float*)alloc((size_t)NN * 4);
  unsigned short* mub = (unsigned short*)alloc((size_t)KK * HH * 2);
  unsigned short* mubT = (unsigned short*)alloc((size_t)KK * HH * 2);
  float* cluster_r = (float*)alloc(KK * 4);
  float* colsum = (float*)alloc(HH * 4);
  float* gs = (float*)alloc(HH * 4);
  float* Ws = (float*)alloc(HH * 4);
  float* loss_accum = (float*)alloc(16);

  hipMemsetAsync(colsum, 0, HH * sizeof(float), stream);
  hipMemsetAsync(loss_accum, 0, sizeof(float), stream);

  prep_kernel<<<256, 256, 0, stream>>>(pos, inv_norm, colsum);
  convert_kernel<<<dim3(PADN / 64, HH / 64), 256, 0, stream>>>(pos, inv_norm, posb, posbT);
  gs_kernel<<<1, 512, 0, stream>>>(colsum, gs);
  wsum_kernel<<<128, 256, 0, stream>>>(W, gs, Ws);

  norm_mu_kernel<<<KK, 256, 0, stream>>>(init, mub, cluster_r);
  for (int it = 0; it < ITERS; ++it) {
    dist_mfma<<<NBLK, 256, 0, stream>>>(posb, mub, rbf, rbfT, cluster_r, it == ITERS - 1 ? 1 : 0);
    muup_mfma<<<dim3(4, NSPLIT), 256, 0, stream>>>(rbfT, posbT, part);
    finorm_kernel<<<KK, 256, 0, stream>>>(part, cluster_r, mub, mubT, it == ITERS - 1 ? 1 : 0);
  }

  loss_mfma<<<NBLK, 512, 0, stream>>>(rbf, mubT, posb, neg, inv_norm, Ws, loss_accum);
  out_kernel<<<1, 1, 0, stream>>>(loss_accum, out);
}